// Round 8
// baseline (741.707 us; speedup 1.0000x reference)
//
#include <hip/hip_runtime.h>

#define N1V 100000
#define N2V 500
#define NEV 1000000
#define ALPHAV 0.2f
#define NB 256        // histogram/scatter blocks
#define CHUNK 3907    // ceil(NEV/NB)
#define CHD 8         // dst chunks per type
#define GP 132        // As padded stride (k-major)

typedef float f32x4 __attribute__((ext_vector_type(4)));

__device__ __forceinline__ float wave_sum(float v) {
#pragma unroll
  for (int off = 32; off > 0; off >>= 1) v += __shfl_xor(v, off, 64);
  return v;
}

// ---------------- prep: c[320] = a^T @ a_2 ; aT[p*128+j] = a[j*320+p] ----------------
__global__ __launch_bounds__(256) void k_prep(const float* __restrict__ a,
                                              const float* __restrict__ a2,
                                              float* __restrict__ c,
                                              float* __restrict__ aT) {
  int b = blockIdx.x;
  if (b < 160) {
    int id = b * 256 + threadIdx.x;          // 0..40959
    int p = id >> 7, j = id & 127;
    aT[id] = a[j * 320 + p];
  } else {
    int p = (b - 160) * 256 + threadIdx.x;   // 0..511
    if (p < 320) {
      float s = 0.f;
      for (int k = 0; k < 128; ++k) s += a2[k] * a[k * 320 + p];
      c[p] = s;
    }
  }
}

// ---------------- z2[t] = x2[t].c2 ; z1[i] = x1[i].c1 ----------------
__global__ __launch_bounds__(256) void k_z2(const float* __restrict__ x2,
                                            const float* __restrict__ c,
                                            float* __restrict__ z2g) {
  int w = (blockIdx.x * 256 + threadIdx.x) >> 6;
  int l = threadIdx.x & 63;
  if (w >= N2V) return;
  float p = x2[(size_t)w * 128 + l] * c[128 + l] + x2[(size_t)w * 128 + 64 + l] * c[192 + l];
  float s = wave_sum(p);
  if (l == 0) z2g[w] = s;
}

__global__ __launch_bounds__(256) void k_z1(const float* __restrict__ x1,
                                            const float* __restrict__ c,
                                            float* __restrict__ z1g) {
  int w = (blockIdx.x * 256 + threadIdx.x) >> 6;
  int l = threadIdx.x & 63;
  if (w >= N1V) return;
  float p = x1[(size_t)w * 128 + l] * c[l] + x1[(size_t)w * 128 + 64 + l] * c[64 + l];
  float s = wave_sum(p);
  if (l == 0) z1g[w] = s;
}

// ---------------- histogram: global atomics for src (100K buckets), LDS for dst ----------------
__global__ __launch_bounds__(256) void k_hist(const int* __restrict__ src,
                                              const int* __restrict__ dst,
                                              int* __restrict__ c1,
                                              int* __restrict__ hblk) {
  __shared__ int h[512];
  for (int i = threadIdx.x; i < 512; i += 256) h[i] = 0;
  __syncthreads();
  int b = blockIdx.x;
  int b0 = b * CHUNK, b1 = min(b0 + CHUNK, NEV);
  for (int e = b0 + threadIdx.x; e < b1; e += 256) {
    atomicAdd(&c1[src[e]], 1);
    atomicAdd(&h[dst[e]], 1);
  }
  __syncthreads();
  for (int i = threadIdx.x; i < 512; i += 256) hblk[b * 512 + i] = h[i];
}

// ---------------- column scan: hblk[b][t] -> exclusive prefix over b; tot2[t] ----------------
__global__ __launch_bounds__(256) void k_colscan(int* __restrict__ hblk,
                                                 int* __restrict__ tot2) {
  __shared__ int s[256];
  int t = blockIdx.x;            // 0..511
  int b = threadIdx.x;           // 0..255
  int v = hblk[b * 512 + t];
  s[b] = v; __syncthreads();
  for (int off = 1; off < 256; off <<= 1) {
    int tv = (b >= off) ? s[b - off] : 0;
    __syncthreads();
    if (b >= off) s[b] += tv;
    __syncthreads();
  }
  hblk[b * 512 + t] = s[b] - v;      // exclusive over blocks
  if (b == 255) tot2[t] = s[255];
}

// ---------------- scan for src counts ----------------
__global__ __launch_bounds__(256) void k_scanA(const int* __restrict__ cnt,
                                               int* __restrict__ outp,
                                               int* __restrict__ partials, int n) {
  __shared__ int s[256];
  int tid = threadIdx.x;
  int base = blockIdx.x * 2048 + tid * 8;
  int v[8]; int tot = 0;
#pragma unroll
  for (int j = 0; j < 8; ++j) { int idx = base + j; v[j] = (idx < n) ? cnt[idx] : 0; tot += v[j]; }
  s[tid] = tot; __syncthreads();
  for (int off = 1; off < 256; off <<= 1) {
    int tv = 0;
    if (tid >= off) tv = s[tid - off];
    __syncthreads();
    if (tid >= off) s[tid] += tv;
    __syncthreads();
  }
  int run = s[tid] - tot;
#pragma unroll
  for (int j = 0; j < 8; ++j) { int idx = base + j; if (idx < n) outp[idx] = run; run += v[j]; }
  if (tid == 255) partials[blockIdx.x] = s[255];
}

__global__ __launch_bounds__(512) void k_scanB(int* __restrict__ partials, int nPart,
                                               const int* __restrict__ tot2,
                                               int* __restrict__ rp2) {
  __shared__ int s[512];
  int tid = threadIdx.x;
  int v = (tid < N2V) ? tot2[tid] : 0;
  s[tid] = v; __syncthreads();
  for (int off = 1; off < 512; off <<= 1) {
    int tv = 0;
    if (tid >= off) tv = s[tid - off];
    __syncthreads();
    if (tid >= off) s[tid] += tv;
    __syncthreads();
  }
  if (tid < N2V) rp2[tid] = s[tid] - v;
  if (tid == N2V - 1) rp2[N2V] = s[tid];
  if (tid == 0) {
    int run = 0;
    for (int b = 0; b < nPart; ++b) { int t = partials[b]; partials[b] = run; run += t; }
  }
}

__global__ __launch_bounds__(256) void k_scanC(int* __restrict__ rp, int* __restrict__ cur,
                                               const int* __restrict__ partials, int n, int total) {
  int i = blockIdx.x * 256 + threadIdx.x;
  if (i < n) {
    int v = rp[i] + partials[i >> 11];
    rp[i] = v; cur[i] = v;
  }
  if (i == 0) rp[n] = total;
}

// ---------------- fused scatter: z3 dot + w + CSR placement + slot-ordered (w,partner) ----------------
__global__ __launch_bounds__(256) void k_scatter(const int* __restrict__ src,
                                                 const int* __restrict__ dst,
                                                 const float* __restrict__ ee,
                                                 const float* __restrict__ z1g,
                                                 const float* __restrict__ z2g,
                                                 const float* __restrict__ c,
                                                 int* __restrict__ cur1,
                                                 const int* __restrict__ hblk,
                                                 const int* __restrict__ rp2,
                                                 int* __restrict__ e1, int* __restrict__ e2,
                                                 float2* __restrict__ wd1,
                                                 float2* __restrict__ wd2) {
  __shared__ int h[512];
  __shared__ int basep[512];
  int b = blockIdx.x;
  int b0 = b * CHUNK, b1 = min(b0 + CHUNK, NEV);
  for (int i = threadIdx.x; i < 512; i += 256) {
    basep[i] = ((i < N2V) ? rp2[i] : 0) + hblk[b * 512 + i];
    h[i] = 0;
  }
  __syncthreads();
  for (int e = b0 + threadIdx.x; e < b1; e += 256) {
    int sv = src[e], d = dst[e];
    const f32x4* row = (const f32x4*)(ee + (size_t)e * 64);
    float d0 = 0.f, d1 = 0.f, d2 = 0.f, d3 = 0.f;
#pragma unroll
    for (int q = 0; q < 4; ++q) {
      f32x4 f0 = __builtin_nontemporal_load(row + 4 * q + 0);
      f32x4 f1 = __builtin_nontemporal_load(row + 4 * q + 1);
      f32x4 f2 = __builtin_nontemporal_load(row + 4 * q + 2);
      f32x4 f3 = __builtin_nontemporal_load(row + 4 * q + 3);
      d0 += f0.x * c[256 + 16 * q + 0] + f0.y * c[256 + 16 * q + 1] +
            f0.z * c[256 + 16 * q + 2] + f0.w * c[256 + 16 * q + 3];
      d1 += f1.x * c[256 + 16 * q + 4] + f1.y * c[256 + 16 * q + 5] +
            f1.z * c[256 + 16 * q + 6] + f1.w * c[256 + 16 * q + 7];
      d2 += f2.x * c[256 + 16 * q + 8] + f2.y * c[256 + 16 * q + 9] +
            f2.z * c[256 + 16 * q + 10] + f2.w * c[256 + 16 * q + 11];
      d3 += f3.x * c[256 + 16 * q + 12] + f3.y * c[256 + 16 * q + 13] +
            f3.z * c[256 + 16 * q + 14] + f3.w * c[256 + 16 * q + 15];
    }
    float z = z1g[sv] + z2g[d] + ((d0 + d1) + (d2 + d3));
    float zp = z > 0.f ? z : ALPHAV * z;
    float w = __expf(-zp);
    int p = atomicAdd(&cur1[sv], 1);
    e1[p] = e;
    wd1[p] = make_float2(w, __int_as_float(d));
    int loc = atomicAdd(&h[d], 1);
    int q2 = basep[d] + loc;
    e2[q2] = e;
    wd2[q2] = make_float2(w, __int_as_float(sv));
  }
}

// ---------------- dst-grouped pure gather pass (no shfl, no exp) ----------------
__global__ __launch_bounds__(256) void k_dst(const float* __restrict__ x1,
                                             const float* __restrict__ ee,
                                             const int* __restrict__ rp2,
                                             const int* __restrict__ e2,
                                             const float2* __restrict__ wd2,
                                             float* __restrict__ acc2) {
  __shared__ float red[4][224];
  int t = blockIdx.x / CHD;
  int chunk = blockIdx.x % CHD;
  int tid = threadIdx.x, wv = tid >> 6, l = tid & 63;
  int start = rp2[t], end = rp2[t + 1];
  int n = end - start;
  int sub = chunk * 4 + wv;                                  // 0..31
  int i0 = start + (int)(((long long)n * sub) >> 5);
  int i1 = start + (int)(((long long)n * (sub + 1)) >> 5);
  float sxa = 0.f, sxb = 0.f, s3 = 0.f, rsum = 0.f;
  int p = i0;
  for (; p + 4 <= i1; p += 4) {
    int ea = e2[p], eb = e2[p + 1], ec = e2[p + 2], ed = e2[p + 3];
    float2 qa = wd2[p], qb = wd2[p + 1], qc = wd2[p + 2], qd = wd2[p + 3];
    int sa = __float_as_int(qa.y), sb = __float_as_int(qb.y);
    int sc = __float_as_int(qc.y), sd = __float_as_int(qd.y);
    float eva = __builtin_nontemporal_load(ee + (size_t)ea * 64 + l);
    float evb = __builtin_nontemporal_load(ee + (size_t)eb * 64 + l);
    float evc = __builtin_nontemporal_load(ee + (size_t)ec * 64 + l);
    float evd = __builtin_nontemporal_load(ee + (size_t)ed * 64 + l);
    float xaa = x1[(size_t)sa * 128 + l], xba = x1[(size_t)sa * 128 + 64 + l];
    float xab = x1[(size_t)sb * 128 + l], xbb = x1[(size_t)sb * 128 + 64 + l];
    float xac = x1[(size_t)sc * 128 + l], xbc = x1[(size_t)sc * 128 + 64 + l];
    float xad = x1[(size_t)sd * 128 + l], xbd = x1[(size_t)sd * 128 + 64 + l];
    rsum += (qa.x + qb.x) + (qc.x + qd.x);
    s3 += qa.x * eva + qb.x * evb + qc.x * evc + qd.x * evd;
    sxa += qa.x * xaa + qb.x * xab + qc.x * xac + qd.x * xad;
    sxb += qa.x * xba + qb.x * xbb + qc.x * xbc + qd.x * xbd;
  }
  for (; p < i1; ++p) {
    int ea = e2[p];
    float2 qa = wd2[p];
    int sa = __float_as_int(qa.y);
    float eva = __builtin_nontemporal_load(ee + (size_t)ea * 64 + l);
    rsum += qa.x;
    s3 += qa.x * eva;
    sxa += qa.x * x1[(size_t)sa * 128 + l];
    sxb += qa.x * x1[(size_t)sa * 128 + 64 + l];
  }
  red[wv][l] = sxa; red[wv][64 + l] = sxb; red[wv][128 + l] = s3;
  if (l == 0) red[wv][192] = rsum;
  __syncthreads();
  if (tid < 193) {
    float v = red[0][tid] + red[1][tid] + red[2][tid] + red[3][tid];
    if (v != 0.f) atomicAdd(&acc2[t * 256 + tid], v);
  }
}

// ---------------- dst finalize ----------------
__global__ __launch_bounds__(256) void k_dst_final(const float* __restrict__ acc2,
                                                   float* __restrict__ sbuf2,
                                                   float* __restrict__ rs2) {
  int t = blockIdx.x, tid = threadIdx.x;
  float rtot = acc2[t * 256 + 192];
  float scale = rtot > 0.f ? 1.0f / rtot : 0.f;
  if (tid < 192) sbuf2[t * 192 + tid] = acc2[t * 256 + tid] * scale;
  if (tid == 192) rs2[t] = rtot;
}

// ---------------- src-grouped pure gather pass ----------------
__global__ __launch_bounds__(256) void k_src(const float* __restrict__ x2,
                                             const float* __restrict__ ee,
                                             const int* __restrict__ rp1,
                                             const int* __restrict__ e1,
                                             const float2* __restrict__ wd1,
                                             float* __restrict__ sbuf1,
                                             float* __restrict__ rs1) {
  int wid = (blockIdx.x * 256 + threadIdx.x) >> 6;
  int l = threadIdx.x & 63;
  if (wid >= N1V) return;
  int start = rp1[wid], end = rp1[wid + 1];
  float s2a = 0.f, s2b = 0.f, s1 = 0.f, rsum = 0.f;
  int p = start;
  for (; p + 4 <= end; p += 4) {
    int ea = e1[p], eb = e1[p + 1], ec = e1[p + 2], ed = e1[p + 3];
    float2 qa = wd1[p], qb = wd1[p + 1], qc = wd1[p + 2], qd = wd1[p + 3];
    int da = __float_as_int(qa.y), db = __float_as_int(qb.y);
    int dc = __float_as_int(qc.y), dd = __float_as_int(qd.y);
    float eva = __builtin_nontemporal_load(ee + (size_t)ea * 64 + l);
    float evb = __builtin_nontemporal_load(ee + (size_t)eb * 64 + l);
    float evc = __builtin_nontemporal_load(ee + (size_t)ec * 64 + l);
    float evd = __builtin_nontemporal_load(ee + (size_t)ed * 64 + l);
    float xaa = x2[(size_t)da * 128 + l], xba = x2[(size_t)da * 128 + 64 + l];
    float xab = x2[(size_t)db * 128 + l], xbb = x2[(size_t)db * 128 + 64 + l];
    float xac = x2[(size_t)dc * 128 + l], xbc = x2[(size_t)dc * 128 + 64 + l];
    float xad = x2[(size_t)dd * 128 + l], xbd = x2[(size_t)dd * 128 + 64 + l];
    rsum += (qa.x + qb.x) + (qc.x + qd.x);
    s1 += qa.x * eva + qb.x * evb + qc.x * evc + qd.x * evd;
    s2a += qa.x * xaa + qb.x * xab + qc.x * xac + qd.x * xad;
    s2b += qa.x * xba + qb.x * xbb + qc.x * xbc + qd.x * xbd;
  }
  for (; p < end; ++p) {
    int ea = e1[p];
    float2 qa = wd1[p];
    int da = __float_as_int(qa.y);
    rsum += qa.x;
    s1 += qa.x * __builtin_nontemporal_load(ee + (size_t)ea * 64 + l);
    s2a += qa.x * x2[(size_t)da * 128 + l];
    s2b += qa.x * x2[(size_t)da * 128 + 64 + l];
  }
  float scale = (end > start) ? 1.0f / rsum : 0.f;
  sbuf1[(size_t)wid * 192 + l] = s2a * scale;
  sbuf1[(size_t)wid * 192 + 64 + l] = s2b * scale;
  sbuf1[(size_t)wid * 192 + 128 + l] = s1 * scale;
  if (l == 0) rs1[wid] = (end > start) ? rsum : 0.f;
}

// ---------------- fused output GEMM: out = mask * elu(A[M,320] @ a^T) ----------------
__global__ __launch_bounds__(256, 4) void k_gemm(const float* __restrict__ X,
                                                 const float* __restrict__ S,
                                                 const float* __restrict__ aT,
                                                 const float* __restrict__ rs,
                                                 float* __restrict__ out,
                                                 int M, int mode) {
  __shared__ float As[32 * GP];
  __shared__ float Bs[32 * 128];
  int tid = threadIdx.x;
  int row0 = blockIdx.x * 128;
  int tm = (tid >> 4) << 3;     // 0,8,...,120
  int tn = (tid & 15) << 2;     // 0,4,...,60
  float acc[8][8];
#pragma unroll
  for (int r = 0; r < 8; ++r)
#pragma unroll
    for (int cc = 0; cc < 8; ++cc) acc[r][cc] = 0.f;

  for (int k0 = 0; k0 < 320; k0 += 32) {
    {
      const float4* bsrc = (const float4*)(aT + k0 * 128);
      float4* bdst = (float4*)Bs;
#pragma unroll
      for (int q = 0; q < 4; ++q) bdst[tid + 256 * q] = bsrc[tid + 256 * q];
    }
#pragma unroll
    for (int q = 0; q < 4; ++q) {
      int t0 = tid + 256 * q;
      int m = t0 >> 3;
      int kq = (t0 & 7) << 2;
      int gi = row0 + m;
      int p = k0 + kq;
      float4 v = make_float4(0.f, 0.f, 0.f, 0.f);
      if (gi < M) {
        const float* sp;
        if (mode == 0) sp = (p < 128) ? (X + (size_t)gi * 128 + p) : (S + (size_t)gi * 192 + (p - 128));
        else sp = (p >= 128 && p < 256) ? (X + (size_t)gi * 128 + (p - 128))
                                        : (S + (size_t)gi * 192 + (p < 128 ? p : p - 128));
        v = *(const float4*)sp;
      }
      As[(kq + 0) * GP + m] = v.x;
      As[(kq + 1) * GP + m] = v.y;
      As[(kq + 2) * GP + m] = v.z;
      As[(kq + 3) * GP + m] = v.w;
    }
    __syncthreads();
#pragma unroll 8
    for (int kk = 0; kk < 32; ++kk) {
      float4 a0 = *(const float4*)&As[kk * GP + tm];
      float4 a1 = *(const float4*)&As[kk * GP + tm + 4];
      float4 b0 = *(const float4*)&Bs[kk * 128 + tn];
      float4 b1 = *(const float4*)&Bs[kk * 128 + 64 + tn];
      float af[8] = {a0.x, a0.y, a0.z, a0.w, a1.x, a1.y, a1.z, a1.w};
      float bf[8] = {b0.x, b0.y, b0.z, b0.w, b1.x, b1.y, b1.z, b1.w};
#pragma unroll
      for (int r = 0; r < 8; ++r)
#pragma unroll
        for (int cc = 0; cc < 8; ++cc) acc[r][cc] += af[r] * bf[cc];
    }
    __syncthreads();
  }
#pragma unroll
  for (int r = 0; r < 8; ++r) {
    int gi = row0 + tm + r;
    if (gi < M) {
      float rsv = rs[gi];
      bool ok = rsv > 0.f;
      float4 o0, o1;
      float h;
      h = acc[r][0]; o0.x = ok ? (h > 0.f ? h : expm1f(h)) : 0.f;
      h = acc[r][1]; o0.y = ok ? (h > 0.f ? h : expm1f(h)) : 0.f;
      h = acc[r][2]; o0.z = ok ? (h > 0.f ? h : expm1f(h)) : 0.f;
      h = acc[r][3]; o0.w = ok ? (h > 0.f ? h : expm1f(h)) : 0.f;
      h = acc[r][4]; o1.x = ok ? (h > 0.f ? h : expm1f(h)) : 0.f;
      h = acc[r][5]; o1.y = ok ? (h > 0.f ? h : expm1f(h)) : 0.f;
      h = acc[r][6]; o1.z = ok ? (h > 0.f ? h : expm1f(h)) : 0.f;
      h = acc[r][7]; o1.w = ok ? (h > 0.f ? h : expm1f(h)) : 0.f;
      *(float4*)(out + (size_t)gi * 128 + tn) = o0;
      *(float4*)(out + (size_t)gi * 128 + 64 + tn) = o1;
    }
  }
}

// =====================================================================================

static inline size_t align_up(size_t x, size_t a) { return (x + a - 1) & ~(a - 1); }

extern "C" void kernel_launch(void* const* d_in, const int* in_sizes, int n_in,
                              void* d_out, int out_size, void* d_ws, size_t ws_size,
                              hipStream_t stream) {
  const float* x1 = (const float*)d_in[0];
  const float* x2 = (const float*)d_in[1];
  const float* ee = (const float*)d_in[2];
  const float* a = (const float*)d_in[3];
  const float* a2 = (const float*)d_in[4];
  const int* esrc = (const int*)d_in[5];
  const int* edst = (const int*)d_in[6];
  float* out = (float*)d_out;

  char* base = (char*)d_ws;
  size_t off = 0;
  auto alloc = [&](size_t bytes) -> char* {
    char* p = base + off;
    off = align_up(off + bytes, 256);
    return p;
  };
  float* c = (float*)alloc(320 * 4);
  float* z1g = (float*)alloc(N1V * 4);
  float* z2g = (float*)alloc(512 * 4);
  float* aT = (float*)alloc(320 * 128 * 4);
  int* rp1 = (int*)alloc((N1V + 1) * 4);
  int* cur1 = (int*)alloc(N1V * 4);
  int* rp2 = (int*)alloc(512 * 4);
  int* partials = (int*)alloc(64 * 4);
  int* hblk = (int*)alloc((size_t)NB * 512 * 4);
  int* tot2 = (int*)alloc(512 * 4);
  int* e1 = (int*)alloc(NEV * 4);
  int* e2 = (int*)alloc(NEV * 4);
  float2* wd1 = (float2*)alloc((size_t)NEV * 8);
  float2* wd2 = (float2*)alloc((size_t)NEV * 8);
  float* rs1 = (float*)alloc(N1V * 4);
  float* rs2 = (float*)alloc(512 * 4);
  float* sbuf1 = (float*)alloc((size_t)N1V * 192 * 4);
  float* sbuf2 = (float*)alloc(512 * 192 * 4);
  float* acc2 = (float*)alloc(512 * 256 * 4);
  (void)ws_size; (void)out_size; (void)n_in; (void)in_sizes;

  hipMemsetAsync(cur1, 0, N1V * 4, stream);
  hipMemsetAsync(acc2, 0, 512 * 256 * 4, stream);

  hipLaunchKernelGGL(k_prep, dim3(162), dim3(256), 0, stream, a, a2, c, aT);
  hipLaunchKernelGGL(k_z2, dim3(125), dim3(256), 0, stream, x2, c, z2g);
  hipLaunchKernelGGL(k_z1, dim3(25000), dim3(256), 0, stream, x1, c, z1g);
  hipLaunchKernelGGL(k_hist, dim3(NB), dim3(256), 0, stream, esrc, edst, cur1, hblk);
  hipLaunchKernelGGL(k_colscan, dim3(512), dim3(256), 0, stream, hblk, tot2);

  const int nScanBlocks = (N1V + 2047) / 2048;  // 49
  hipLaunchKernelGGL(k_scanA, dim3(nScanBlocks), dim3(256), 0, stream, cur1, rp1, partials, N1V);
  hipLaunchKernelGGL(k_scanB, dim3(1), dim3(512), 0, stream, partials, nScanBlocks, tot2, rp2);
  hipLaunchKernelGGL(k_scanC, dim3((N1V + 255) / 256), dim3(256), 0, stream, rp1, cur1, partials, N1V, NEV);
  hipLaunchKernelGGL(k_scatter, dim3(NB), dim3(256), 0, stream,
                     esrc, edst, ee, z1g, z2g, c, cur1, hblk, rp2, e1, e2, wd1, wd2);

  hipLaunchKernelGGL(k_dst, dim3(N2V * CHD), dim3(256), 0, stream,
                     x1, ee, rp2, e2, wd2, acc2);
  hipLaunchKernelGGL(k_dst_final, dim3(N2V), dim3(256), 0, stream, acc2, sbuf2, rs2);

  hipLaunchKernelGGL(k_src, dim3(N1V / 4), dim3(256), 0, stream,
                     x2, ee, rp1, e1, wd1, sbuf1, rs1);

  hipLaunchKernelGGL(k_gemm, dim3((N1V + 127) / 128), dim3(256), 0, stream,
                     x1, sbuf1, aT, rs1, out, N1V, 0);
  hipLaunchKernelGGL(k_gemm, dim3((N2V + 127) / 128), dim3(256), 0, stream,
                     x2, sbuf2, aT, rs2, out + (size_t)N1V * 128, N2V, 1);
}